// Round 8
// baseline (1288.122 us; speedup 1.0000x reference)
//
#include <hip/hip_runtime.h>
#include <hip/hip_fp16.h>
#include <hip/hip_cooperative_groups.h>
#include <cstdint>
#include <cstddef>

namespace cg = cooperative_groups;

#define PP 9216
#define NPRIM 5
#define NITER 10
#define IMG 9216

typedef float vf4 __attribute__((ext_vector_type(4)));
union H8 { vf4 f4; __half h[8]; };

// ---------------- shared-memory phase union ----------------
struct ShEv { float img[576]; float red[240][8]; };
struct ShBp { float d2[PP]; float red[216]; };
struct ShCv { float c1s[32*10*12]; float c2s[32*8*9]; float ovl[9216];
              float b1[32], b2[32], b3[5], al[2]; };
union Sh { ShEv ev; ShBp bp; ShCv cv; };

// ---------------- ev1 task: (a, c) chunk partial ----------------
// ev1[a,x] = sum_p Snorm[a,0,p,x] * img[p], img[p] = primal[ch1][h,w], p = w*96+h
template<int MODE>
__device__ void ev1_task(ShEv& S, int a, int c,
                         const float* __restrict__ Sf, __half* __restrict__ S16,
                         const float* __restrict__ prim, float* __restrict__ part){
  const int p0 = c*576;
  const int tid = threadIdx.x;
  const float* prim1 = prim + IMG; // channel 1
  __syncthreads();   // protect LDS reuse across sequential tasks
  for (int idx = tid; idx < 576; idx += 256){
    int p = p0 + idx;
    int h = p % 96, w = p / 96;
    S.img[idx] = prim1[h*96 + w];
  }
  __syncthreads();
  if (tid < 240){
    const int xg = tid % 12, pr = tid / 12;   // 12 x 8 halves = 96, pr: 0..19
    float acc[8];
    #pragma unroll
    for (int j = 0; j < 8; ++j) acc[j] = 0.f;
    const size_t base = ((size_t)a*PP + p0)*96 + 8*xg;
    #pragma unroll 4
    for (int pi = pr; pi < 576; pi += 20){
      float s[8];
      if (MODE == 2){
        H8 u; u.f4 = __builtin_nontemporal_load(reinterpret_cast<const vf4*>(S16 + base + (size_t)pi*96));
        #pragma unroll
        for (int j = 0; j < 8; ++j) s[j] = __half2float(u.h[j]);
      } else {
        const vf4 q0 = __builtin_nontemporal_load(reinterpret_cast<const vf4*>(Sf + base + (size_t)pi*96));
        const vf4 q1 = __builtin_nontemporal_load(reinterpret_cast<const vf4*>(Sf + base + (size_t)pi*96 + 4));
        float t[8] = {q0.x,q0.y,q0.z,q0.w,q1.x,q1.y,q1.z,q1.w};
        if (MODE == 1){
          H8 u;
          #pragma unroll
          for (int j = 0; j < 8; ++j){ u.h[j] = __float2half(t[j]); s[j] = __half2float(u.h[j]); }
          __builtin_nontemporal_store(u.f4, reinterpret_cast<vf4*>(S16 + base + (size_t)pi*96));
        } else {
          #pragma unroll
          for (int j = 0; j < 8; ++j) s[j] = t[j];
        }
      }
      const float im = S.img[pi];
      #pragma unroll
      for (int j = 0; j < 8; ++j) acc[j] += im*s[j];
    }
    #pragma unroll
    for (int j = 0; j < 8; ++j) S.red[tid][j] = acc[j];
  }
  __syncthreads();
  if (tid < 12){
    float r[8];
    #pragma unroll
    for (int j = 0; j < 8; ++j) r[j] = S.red[tid][j];
    for (int q = 1; q < 20; ++q)
      #pragma unroll
      for (int j = 0; j < 8; ++j) r[j] += S.red[tid + 12*q][j];
    float* dst = &part[((size_t)a*16 + c)*96 + 8*tid];
    vf4 v0 = {r[0],r[1],r[2],r[3]}, v1 = {r[4],r[5],r[6],r[7]};
    *reinterpret_cast<vf4*>(dst) = v0;
    *reinterpret_cast<vf4*>(dst+4) = v1;
  }
}

// ---------------- bp compute: task t covers p-rows [t*18, t*18+18); d2 preloaded ----------------
// bp[p] = sum_{a,x} S[a,0,p,x]*dual[a,x]; ev2 image [h][w] = bp[w*96+h]
template<int MODE>
__device__ void bp_compute(ShBp& S, int t,
                           const float* __restrict__ Sf, __half* __restrict__ S16,
                           float* __restrict__ ev2){
  const int tid = threadIdx.x;
  __syncthreads();   // protect red reuse across sequential tasks
  const int p0 = t * 18;
  if (tid < 216){
    const int xg = tid % 12, pr = tid / 12;   // 12 x 8 halves = 96, pr: 0..17
    const int p = p0 + pr;
    float acc = 0.f;
    const size_t base = (size_t)p*96 + 8*xg;
    const size_t astr = (size_t)PP*96;
    #pragma unroll 4
    for (int a = 0; a < 96; ++a){
      float s[8];
      if (MODE == 2){
        H8 u; u.f4 = __builtin_nontemporal_load(reinterpret_cast<const vf4*>(S16 + base + (size_t)a*astr));
        #pragma unroll
        for (int j = 0; j < 8; ++j) s[j] = __half2float(u.h[j]);
      } else {
        const vf4 q0 = __builtin_nontemporal_load(reinterpret_cast<const vf4*>(Sf + base + (size_t)a*astr));
        const vf4 q1 = __builtin_nontemporal_load(reinterpret_cast<const vf4*>(Sf + base + (size_t)a*astr + 4));
        float tt[8] = {q0.x,q0.y,q0.z,q0.w,q1.x,q1.y,q1.z,q1.w};
        if (MODE == 1){
          H8 u;
          #pragma unroll
          for (int j = 0; j < 8; ++j){ u.h[j] = __float2half(tt[j]); s[j] = __half2float(u.h[j]); }
          __builtin_nontemporal_store(u.f4, reinterpret_cast<vf4*>(S16 + base + (size_t)a*astr));
        } else {
          #pragma unroll
          for (int j = 0; j < 8; ++j) s[j] = tt[j];
        }
      }
      const vf4 da = *reinterpret_cast<const vf4*>(&S.d2[a*96 + 8*xg]);
      const vf4 db = *reinterpret_cast<const vf4*>(&S.d2[a*96 + 8*xg + 4]);
      acc += s[0]*da.x + s[1]*da.y + s[2]*da.z + s[3]*da.w
           + s[4]*db.x + s[5]*db.y + s[6]*db.z + s[7]*db.w;
    }
    S.red[tid] = acc;
  }
  __syncthreads();
  if (tid < 18){
    float s = 0.f;
    #pragma unroll
    for (int j = 0; j < 12; ++j) s += S.red[tid*12 + j];
    int pp = p0 + tid;
    int h = pp % 96, w = pp / 96;
    ev2[h*96 + w] = s;
  }
}

__device__ void bp_load(ShBp& S, const float* __restrict__ dual){
  __syncthreads();
  for (int i = threadIdx.x; i < PP/4; i += 256)
    reinterpret_cast<vf4*>(S.d2)[i] = reinterpret_cast<const vf4*>(dual)[i];
  __syncthreads();
}

// ---------------- fused conv block task (6x6 tile) ----------------
// Each conv layer zero-pads its OWN input ('SAME'): intermediate values at
// out-of-image positions are forced to ZERO.
template<int CIN, int COUT, bool REDB>
__device__ void conv_task(ShCv& S, int x0, int y0,
    const float* __restrict__ inA, int nA, const float* __restrict__ inB, int nB,
    const float* __restrict__ inC,
    const float* __restrict__ W1, const float* __restrict__ B1, const float* __restrict__ A1,
    const float* __restrict__ W2, const float* __restrict__ B2, const float* __restrict__ A2,
    const float* __restrict__ W3, const float* __restrict__ B3,
    float* __restrict__ out, float* __restrict__ out2)
{
  constexpr int XINF = CIN*144;    // input tile [CIN][12][12]
  constexpr int W1F  = 32*CIN*9;
  constexpr int W3F  = COUT*32*9;

  const int tid = threadIdx.x;
  float* xin = S.ovl;            // [CIN][12][12]
  float* w1s = S.ovl + XINF;

  __syncthreads();
  // ---- load input tile (zero-padded) + w1 + biases/alphas ----
  for (int i = tid; i < XINF; i += 256){
    int ch = i / 144, r = (i % 144) / 12, cc = i % 12;
    int gy = y0 - 3 + r, gx = x0 - 3 + cc;
    float v = 0.f;
    if (gy >= 0 && gy < 96 && gx >= 0 && gx < 96){
      if (REDB && ch >= nA && ch < nA + nB){
        float s = 0.f;
        #pragma unroll
        for (int cch = 0; cch < 16; ++cch) s += inB[((size_t)gy*16 + cch)*96 + gx];
        v = s;
      } else {
        const float* src = (ch < nA) ? (inA + (size_t)ch*IMG)
                         : (ch < nA+nB) ? (inB + (size_t)(ch-nA)*IMG)
                         : (inC + (size_t)(ch-nA-nB)*IMG);
        v = src[gy*96 + gx];
      }
    }
    xin[i] = v;
  }
  for (int i = tid; i < W1F; i += 256) w1s[i] = W1[i];
  if (tid < 32) S.b1[tid] = B1[tid];
  else if (tid < 64) S.b2[tid-32] = B2[tid-32];
  else if (tid < 64+COUT) S.b3[tid-64] = B3[tid-64];
  else if (tid == 96) S.al[0] = A1[0];
  else if (tid == 97) S.al[1] = A2[0];
  __syncthreads();

  // ---- conv1 (CIN -> 32) + PReLU ----
  {
    const int och = tid & 31, t = tid >> 5;
    const float al = S.al[0];
    for (int r = t; r < 10; r += 8){
      const int gy = y0 - 2 + r;
      float acc[10];
      #pragma unroll
      for (int cc = 0; cc < 10; ++cc) acc[cc] = S.b1[och];
      #pragma unroll
      for (int ci = 0; ci < CIN; ++ci){
        float xr[3][12];
        #pragma unroll
        for (int ky = 0; ky < 3; ++ky){
          #pragma unroll
          for (int j = 0; j < 3; ++j){
            vf4 q = *reinterpret_cast<const vf4*>(&xin[ci*144 + (r+ky)*12 + 4*j]);
            xr[ky][4*j+0]=q.x; xr[ky][4*j+1]=q.y; xr[ky][4*j+2]=q.z; xr[ky][4*j+3]=q.w;
          }
        }
        float wv[9];
        #pragma unroll
        for (int kk = 0; kk < 9; ++kk) wv[kk] = w1s[(och*CIN+ci)*9 + kk];
        #pragma unroll
        for (int ky = 0; ky < 3; ++ky)
          #pragma unroll
          for (int kx = 0; kx < 3; ++kx)
            #pragma unroll
            for (int cc = 0; cc < 10; ++cc)
              acc[cc] += xr[ky][cc+kx] * wv[ky*3+kx];
      }
      const bool yin = (gy >= 0 && gy < 96);
      #pragma unroll
      for (int cc = 0; cc < 10; ++cc){
        const int gx = x0 - 2 + cc;
        float v = acc[cc];
        v = (v >= 0.f) ? v : al*v;
        const bool in = yin && (gx >= 0 && gx < 96);
        S.c1s[(och*10 + r)*12 + cc] = in ? v : 0.f;
      }
    }
  }
  // ---- pull residual into regs before xin is overlaid ----
  float resv = 0.f;
  {
    int sp = tid % 36, och = tid / 36;
    if (och < COUT){
      int ty = sp / 6, tx = sp % 6;
      resv = xin[och*144 + (ty+3)*12 + (tx+3)];
    }
  }
  // ---- coalesced W2 load into registers (before barrier overlays xin) ----
  float w2r[36];
  {
    const vf4* src = reinterpret_cast<const vf4*>(W2 + (size_t)tid*36);
    #pragma unroll
    for (int q = 0; q < 9; ++q) reinterpret_cast<vf4*>(w2r)[q] = src[q];
  }
  __syncthreads();

  // ---- scatter W2 into overlay transposed: w2t[(ci*9+kk)*32 + och] ----
  float* w2t = S.ovl;
  {
    const int och = tid >> 3, k0 = (tid & 7)*36;
    #pragma unroll
    for (int j = 0; j < 36; ++j) w2t[(k0 + j)*32 + och] = w2r[j];
  }
  __syncthreads();

  // ---- conv2 (32 -> 32) + PReLU ----
  {
    const int och = tid & 31, ty = tid >> 5;  // ty 0..7
    const int gy = y0 - 1 + ty;
    const float al = S.al[1];
    float acc[8];
    #pragma unroll
    for (int cc = 0; cc < 8; ++cc) acc[cc] = S.b2[och];
    for (int ci = 0; ci < 32; ++ci){
      float cr[3][12];
      #pragma unroll
      for (int ky = 0; ky < 3; ++ky){
        #pragma unroll
        for (int j = 0; j < 3; ++j){
          vf4 q = *reinterpret_cast<const vf4*>(&S.c1s[(ci*10 + ty+ky)*12 + 4*j]);
          cr[ky][4*j+0]=q.x; cr[ky][4*j+1]=q.y; cr[ky][4*j+2]=q.z; cr[ky][4*j+3]=q.w;
        }
      }
      float wv[9];
      #pragma unroll
      for (int kk = 0; kk < 9; ++kk) wv[kk] = w2t[(ci*9+kk)*32 + och];
      #pragma unroll
      for (int ky = 0; ky < 3; ++ky)
        #pragma unroll
        for (int kx = 0; kx < 3; ++kx)
          #pragma unroll
          for (int cc = 0; cc < 8; ++cc)
            acc[cc] += cr[ky][cc+kx] * wv[ky*3+kx];
    }
    const bool yin = (gy >= 0 && gy < 96);
    #pragma unroll
    for (int cc = 0; cc < 8; ++cc){
      const int gx = x0 - 1 + cc;
      float v = acc[cc];
      v = (v >= 0.f) ? v : al*v;
      const bool in = yin && (gx >= 0 && gx < 96);
      S.c2s[(och*8 + ty)*9 + cc] = in ? v : 0.f;
    }
  }
  __syncthreads();

  // ---- load w3 into overlay ----
  float* w3s = S.ovl;
  for (int i = tid; i < W3F; i += 256) w3s[i] = W3[i];
  __syncthreads();

  // ---- conv3 (32 -> COUT) + bias + residual ----
  {
    int sp = tid % 36, och = tid / 36;
    if (och < COUT){
      int ty = sp / 6, tx = sp % 6;
      float acc = S.b3[och];
      for (int ci = 0; ci < 32; ++ci){
        #pragma unroll
        for (int ky = 0; ky < 3; ++ky)
          #pragma unroll
          for (int kx = 0; kx < 3; ++kx)
            acc += S.c2s[(ci*8 + ty+ky)*9 + (tx+kx)] * w3s[(och*32+ci)*9 + ky*3+kx];
      }
      const float vout = resv + acc;
      const int idx = (y0+ty)*96 + (x0+tx);
      out[(size_t)och*IMG + idx] = vout;
      if (out2 != nullptr && och == 0) out2[idx] = vout;
    }
  }
}

// ---------------- parameter block ----------------
struct P {
  const float *dual, *primal, *proj, *S, *Snorm;
  const float *dW1,*db1,*da1,*dW2,*db2,*da2,*dW3,*db3;
  const float *pW1,*pb1,*pa1,*pW2,*pb2,*pa2,*pW3,*pb3;
  __half *S16n, *S16s;
  float *dB0,*dB1,*pB0,*pB1,*part,*ev2;
  float *outp;
  int f16;
};

// ---------------- cooperative mega-kernel (grid-size agnostic) ----------------
__global__ __launch_bounds__(256) void mega(P p){
  cg::grid_group grid = cg::this_grid();
  __shared__ Sh sh;
  const int bid = blockIdx.x;
  const int nb = gridDim.x;

  for (int k = 0; k < NITER; ++k){
    const float* dcur = (k == 0) ? p.dual   : ((k & 1) ? p.dB0 : p.dB1);
    float*       dnxt = (k & 1) ? p.dB1 : p.dB0;
    const float* pcur = (k == 0) ? p.primal : ((k & 1) ? p.pB0 : p.pB1);
    float*       pnxt = (k & 1) ? p.pB1 : p.pB0;
    float*       out2 = (k == NITER-1) ? p.outp : nullptr;

    // ---- phase E: ev1 partials (1536 tasks) ----
    for (int t = bid; t < 1536; t += nb){
      const int a = t >> 4, c = t & 15;
      if (p.f16){
        if (k == 0) ev1_task<1>(sh.ev, a, c, p.Snorm, p.S16n, pcur, p.part);
        else        ev1_task<2>(sh.ev, a, c, nullptr, p.S16n, pcur, p.part);
      } else        ev1_task<0>(sh.ev, a, c, p.Snorm, nullptr, pcur, p.part);
    }
    grid.sync();

    // ---- phase DC: dual conv block (256 tasks) ----
    for (int t = bid; t < 256; t += nb){
      conv_task<3,1,true>(sh.cv, (t & 15)*6, (t >> 4)*6,
          dcur, 1, p.part, 1, p.proj,
          p.dW1 + (size_t)k*32*3*9, p.db1 + (size_t)k*32, p.da1 + k,
          p.dW2 + (size_t)k*32*32*9, p.db2 + (size_t)k*32, p.da2 + k,
          p.dW3 + (size_t)k*1*32*9, p.db3 + (size_t)k*1, dnxt, nullptr);
    }
    grid.sync();

    // ---- phase B: back projection (512 tasks x 18 rows) ----
    bp_load(sh.bp, dnxt);
    for (int t = bid; t < 512; t += nb){
      if (p.f16){
        if (k == 0) bp_compute<1>(sh.bp, t, p.S, p.S16s, p.ev2);
        else        bp_compute<2>(sh.bp, t, nullptr, p.S16s, p.ev2);
      } else        bp_compute<0>(sh.bp, t, p.S, nullptr, p.ev2);
    }
    grid.sync();

    // ---- phase PC: primal conv block (256 tasks) ----
    for (int t = bid; t < 256; t += nb){
      conv_task<6,5,false>(sh.cv, (t & 15)*6, (t >> 4)*6,
          pcur, 5, p.ev2, 1, p.ev2,
          p.pW1 + (size_t)k*32*6*9, p.pb1 + (size_t)k*32, p.pa1 + k,
          p.pW2 + (size_t)k*32*32*9, p.pb2 + (size_t)k*32, p.pa2 + k,
          p.pW3 + (size_t)k*5*32*9, p.pb3 + (size_t)k*5, pnxt, out2);
    }
    grid.sync();
  }
}

// ---------------- fallback wrappers (round-5 multi-kernel path) ----------------
template<int MODE>
__global__ __launch_bounds__(256) void k_ev1_w(const float* Sf, __half* S16,
                                               const float* prim, float* part){
  __shared__ ShEv sh;
  ev1_task<MODE>(sh, blockIdx.x, blockIdx.y, Sf, S16, prim, part);
}

template<int MODE>
__global__ __launch_bounds__(256) void k_bp_w(const float* Sf, __half* S16,
                                              const float* dual, float* ev2){
  __shared__ ShBp sh;
  bp_load(sh, dual);
  bp_compute<MODE>(sh, blockIdx.x, Sf, S16, ev2);
}

template<int CIN, int COUT, bool REDB>
__global__ __launch_bounds__(256) void k_conv_w(
    const float* inA, int nA, const float* inB, int nB, const float* inC,
    const float* W1, const float* B1, const float* A1,
    const float* W2, const float* B2, const float* A2,
    const float* W3, const float* B3, float* out, float* out2){
  __shared__ ShCv sh;
  conv_task<CIN,COUT,REDB>(sh, (blockIdx.x & 15)*6, (blockIdx.x >> 4)*6,
      inA, nA, inB, nB, inC, W1, B1, A1, W2, B2, A2, W3, B3, out, out2);
}

extern "C" void kernel_launch(void* const* d_in, const int* in_sizes, int n_in,
                              void* d_out, int out_size, void* d_ws, size_t ws_size,
                              hipStream_t stream){
  (void)in_sizes; (void)n_in; (void)out_size;
  P p;
  p.dual   = (const float*)d_in[0];
  p.primal = (const float*)d_in[1];
  p.proj   = (const float*)d_in[2];
  p.S      = (const float*)d_in[3];
  p.Snorm  = (const float*)d_in[4];
  p.dW1 = (const float*)d_in[5];  p.db1 = (const float*)d_in[6];  p.da1 = (const float*)d_in[7];
  p.dW2 = (const float*)d_in[8];  p.db2 = (const float*)d_in[9];  p.da2 = (const float*)d_in[10];
  p.dW3 = (const float*)d_in[11]; p.db3 = (const float*)d_in[12];
  p.pW1 = (const float*)d_in[13]; p.pb1 = (const float*)d_in[14]; p.pa1 = (const float*)d_in[15];
  p.pW2 = (const float*)d_in[16]; p.pb2 = (const float*)d_in[17]; p.pa2 = (const float*)d_in[18];
  p.pW3 = (const float*)d_in[19]; p.pb3 = (const float*)d_in[20];

  const size_t S16E = (size_t)96*PP*96;
  const size_t needFloats = (size_t)29*PP;
  const size_t need16 = 2*S16E*sizeof(__half) + needFloats*sizeof(float);
  p.f16 = (ws_size >= need16) ? 1 : 0;

  float* fbase;
  if (p.f16){
    p.S16n = (__half*)d_ws;
    p.S16s = p.S16n + S16E;
    fbase = (float*)(p.S16s + S16E);
  } else {
    p.S16n = nullptr; p.S16s = nullptr;
    fbase = (float*)d_ws;
  }
  p.dB0  = fbase;            fbase += PP;
  p.dB1  = fbase;            fbase += PP;
  p.pB0  = fbase;            fbase += NPRIM*PP;
  p.pB1  = fbase;            fbase += NPRIM*PP;
  p.part = fbase;            fbase += 16*PP;
  p.ev2  = fbase;            fbase += PP;
  p.outp = (float*)d_out;

  // ---- decide cooperative vs fallback (host queries: deterministic, capture-safe) ----
  int dev = 0; hipGetDevice(&dev);
  int coop = 0; hipDeviceGetAttribute(&coop, hipDeviceAttributeCooperativeLaunch, dev);
  int nCU = 0;  hipDeviceGetAttribute(&nCU, hipDeviceAttributeMultiprocessorCount, dev);
  int mb = 0;
  hipError_t oe = hipOccupancyMaxActiveBlocksPerMultiprocessor(&mb, mega, 256, 0);
  int nblk = 0;
  if (coop && oe == hipSuccess && nCU > 0 && mb > 0){
    long cap = (long)mb * (long)nCU;
    nblk = (cap < 512) ? (int)cap : 512;   // r7 post-mortem: 256 (1 blk/CU) starved HBM streaming
  }

  bool launched = false;
  if (nblk >= 64){
    void* args[] = { &p };
    hipError_t le = hipLaunchCooperativeKernel((const void*)mega, dim3(nblk), dim3(256),
                                               args, 0, stream);
    launched = (le == hipSuccess);
  }

  if (!launched){
    // ---- fallback: round-5 multi-kernel sequence ----
    for (int k = 0; k < NITER; ++k){
      const float* dcur = (k == 0) ? p.dual   : ((k & 1) ? p.dB0 : p.dB1);
      float*       dnxt = (k & 1) ? p.dB1 : p.dB0;
      const float* pcur = (k == 0) ? p.primal : ((k & 1) ? p.pB0 : p.pB1);
      float*       pnxt = (k & 1) ? p.pB1 : p.pB0;
      float*       out2 = (k == NITER-1) ? p.outp : nullptr;

      if (p.f16){
        if (k == 0) k_ev1_w<1><<<dim3(96,16), 256, 0, stream>>>(p.Snorm, p.S16n, pcur, p.part);
        else        k_ev1_w<2><<<dim3(96,16), 256, 0, stream>>>(nullptr, p.S16n, pcur, p.part);
      } else        k_ev1_w<0><<<dim3(96,16), 256, 0, stream>>>(p.Snorm, nullptr, pcur, p.part);

      k_conv_w<3,1,true><<<256, 256, 0, stream>>>(
          dcur, 1, p.part, 1, p.proj,
          p.dW1 + (size_t)k*32*3*9, p.db1 + (size_t)k*32, p.da1 + k,
          p.dW2 + (size_t)k*32*32*9, p.db2 + (size_t)k*32, p.da2 + k,
          p.dW3 + (size_t)k*1*32*9, p.db3 + (size_t)k*1, dnxt, nullptr);

      if (p.f16){
        if (k == 0) k_bp_w<1><<<512, 256, 0, stream>>>(p.S, p.S16s, dnxt, p.ev2);
        else        k_bp_w<2><<<512, 256, 0, stream>>>(nullptr, p.S16s, dnxt, p.ev2);
      } else        k_bp_w<0><<<512, 256, 0, stream>>>(p.S, nullptr, dnxt, p.ev2);

      k_conv_w<6,5,false><<<256, 256, 0, stream>>>(
          pcur, 5, p.ev2, 1, p.ev2,
          p.pW1 + (size_t)k*32*6*9, p.pb1 + (size_t)k*32, p.pa1 + k,
          p.pW2 + (size_t)k*32*32*9, p.pb2 + (size_t)k*32, p.pa2 + k,
          p.pW3 + (size_t)k*5*32*9, p.pb3 + (size_t)k*5, pnxt, out2);
    }
  }
}

// Round 9
// 1122.354 us; speedup vs baseline: 1.1477x; 1.1477x over previous
//
#include <hip/hip_runtime.h>
#include <hip/hip_fp16.h>
#include <cstdint>
#include <cstddef>

#define PP 9216
#define NPRIM 5
#define NITER 10
#define IMG 9216

typedef float vf4 __attribute__((ext_vector_type(4)));
union H8 { vf4 f4; __half h[8]; };

// ---------------- shared structs ----------------
struct ShEv { float img[576]; float red[240][8]; };
struct ShBp { float d2[PP]; float red[216]; };
struct ShCv { float c1s[32*10*12]; float c2s[32*8*9]; float ovl[9216];
              float b1[32], b2[32], b3[5], al[2]; };

// ---------------- ev1 task: (a, c) chunk partial ----------------
// ev1[a,x] = sum_p Snorm[a,0,p,x] * img[p], img[p] = primal[ch1][h,w], p = w*96+h
// MODE 1: read fp32 (nt), round via fp16, write fp16 copy (nt).
// MODE 2: read fp16 copy CACHED (S16n fits in 256MB L3 -> resident across iters).
// MODE 0: pure fp32 fallback.
template<int MODE>
__device__ void ev1_task(ShEv& S, int a, int c,
                         const float* __restrict__ Sf, __half* __restrict__ S16,
                         const float* __restrict__ prim, float* __restrict__ part){
  const int p0 = c*576;
  const int tid = threadIdx.x;
  const float* prim1 = prim + IMG; // channel 1
  for (int idx = tid; idx < 576; idx += 256){
    int p = p0 + idx;
    int h = p % 96, w = p / 96;
    S.img[idx] = prim1[h*96 + w];
  }
  __syncthreads();
  if (tid < 240){
    const int xg = tid % 12, pr = tid / 12;   // 12 x 8 halves = 96, pr: 0..19
    float acc[8];
    #pragma unroll
    for (int j = 0; j < 8; ++j) acc[j] = 0.f;
    const size_t base = ((size_t)a*PP + p0)*96 + 8*xg;
    #pragma unroll 4
    for (int pi = pr; pi < 576; pi += 20){
      float s[8];
      if (MODE == 2){
        // CACHED read: let L3 keep S16n resident across iterations
        H8 u; u.f4 = *reinterpret_cast<const vf4*>(S16 + base + (size_t)pi*96);
        #pragma unroll
        for (int j = 0; j < 8; ++j) s[j] = __half2float(u.h[j]);
      } else {
        const vf4 q0 = __builtin_nontemporal_load(reinterpret_cast<const vf4*>(Sf + base + (size_t)pi*96));
        const vf4 q1 = __builtin_nontemporal_load(reinterpret_cast<const vf4*>(Sf + base + (size_t)pi*96 + 4));
        float t[8] = {q0.x,q0.y,q0.z,q0.w,q1.x,q1.y,q1.z,q1.w};
        if (MODE == 1){
          H8 u;
          #pragma unroll
          for (int j = 0; j < 8; ++j){ u.h[j] = __float2half(t[j]); s[j] = __half2float(u.h[j]); }
          __builtin_nontemporal_store(u.f4, reinterpret_cast<vf4*>(S16 + base + (size_t)pi*96));
        } else {
          #pragma unroll
          for (int j = 0; j < 8; ++j) s[j] = t[j];
        }
      }
      const float im = S.img[pi];
      #pragma unroll
      for (int j = 0; j < 8; ++j) acc[j] += im*s[j];
    }
    #pragma unroll
    for (int j = 0; j < 8; ++j) S.red[tid][j] = acc[j];
  }
  __syncthreads();
  if (tid < 12){
    float r[8];
    #pragma unroll
    for (int j = 0; j < 8; ++j) r[j] = S.red[tid][j];
    for (int q = 1; q < 20; ++q)
      #pragma unroll
      for (int j = 0; j < 8; ++j) r[j] += S.red[tid + 12*q][j];
    float* dst = &part[((size_t)a*16 + c)*96 + 8*tid];
    vf4 v0 = {r[0],r[1],r[2],r[3]}, v1 = {r[4],r[5],r[6],r[7]};
    *reinterpret_cast<vf4*>(dst) = v0;
    *reinterpret_cast<vf4*>(dst+4) = v1;
  }
}

// ---------------- bp: 18 p-rows per block; S16s reads stay NONTEMPORAL ----------------
// bp[p] = sum_{a,x} S[a,0,p,x]*dual[a,x]; ev2 image [h][w] = bp[w*96+h]
template<int MODE>
__device__ void bp_task(ShBp& S, int t,
                        const float* __restrict__ Sf, __half* __restrict__ S16,
                        const float* __restrict__ dual, float* __restrict__ ev2){
  const int tid = threadIdx.x;
  for (int i = tid; i < PP/4; i += 256)
    reinterpret_cast<vf4*>(S.d2)[i] = reinterpret_cast<const vf4*>(dual)[i];
  __syncthreads();
  const int p0 = t * 18;
  if (tid < 216){
    const int xg = tid % 12, pr = tid / 12;   // 12 x 8 halves = 96, pr: 0..17
    const int p = p0 + pr;
    float acc = 0.f;
    const size_t base = (size_t)p*96 + 8*xg;
    const size_t astr = (size_t)PP*96;
    #pragma unroll 4
    for (int a = 0; a < 96; ++a){
      float s[8];
      if (MODE == 2){
        H8 u; u.f4 = __builtin_nontemporal_load(reinterpret_cast<const vf4*>(S16 + base + (size_t)a*astr));
        #pragma unroll
        for (int j = 0; j < 8; ++j) s[j] = __half2float(u.h[j]);
      } else {
        const vf4 q0 = __builtin_nontemporal_load(reinterpret_cast<const vf4*>(Sf + base + (size_t)a*astr));
        const vf4 q1 = __builtin_nontemporal_load(reinterpret_cast<const vf4*>(Sf + base + (size_t)a*astr + 4));
        float tt[8] = {q0.x,q0.y,q0.z,q0.w,q1.x,q1.y,q1.z,q1.w};
        if (MODE == 1){
          H8 u;
          #pragma unroll
          for (int j = 0; j < 8; ++j){ u.h[j] = __float2half(tt[j]); s[j] = __half2float(u.h[j]); }
          __builtin_nontemporal_store(u.f4, reinterpret_cast<vf4*>(S16 + base + (size_t)a*astr));
        } else {
          #pragma unroll
          for (int j = 0; j < 8; ++j) s[j] = tt[j];
        }
      }
      const vf4 da = *reinterpret_cast<const vf4*>(&S.d2[a*96 + 8*xg]);
      const vf4 db = *reinterpret_cast<const vf4*>(&S.d2[a*96 + 8*xg + 4]);
      acc += s[0]*da.x + s[1]*da.y + s[2]*da.z + s[3]*da.w
           + s[4]*db.x + s[5]*db.y + s[6]*db.z + s[7]*db.w;
    }
    S.red[tid] = acc;
  }
  __syncthreads();
  if (tid < 18){
    float s = 0.f;
    #pragma unroll
    for (int j = 0; j < 12; ++j) s += S.red[tid*12 + j];
    int pp = p0 + tid;
    int h = pp % 96, w = pp / 96;
    ev2[h*96 + w] = s;
  }
}

// ---------------- fused conv block task (6x6 tile) ----------------
// Each conv layer zero-pads its OWN input ('SAME'): intermediate values at
// out-of-image positions are forced to ZERO.
template<int CIN, int COUT, bool REDB>
__device__ void conv_task(ShCv& S, int x0, int y0,
    const float* __restrict__ inA, int nA, const float* __restrict__ inB, int nB,
    const float* __restrict__ inC,
    const float* __restrict__ W1, const float* __restrict__ B1, const float* __restrict__ A1,
    const float* __restrict__ W2, const float* __restrict__ B2, const float* __restrict__ A2,
    const float* __restrict__ W3, const float* __restrict__ B3,
    float* __restrict__ out, float* __restrict__ out2)
{
  constexpr int XINF = CIN*144;    // input tile [CIN][12][12]
  constexpr int W1F  = 32*CIN*9;
  constexpr int W3F  = COUT*32*9;

  const int tid = threadIdx.x;
  float* xin = S.ovl;            // [CIN][12][12]
  float* w1s = S.ovl + XINF;

  // ---- load input tile (zero-padded) + w1 + biases/alphas ----
  for (int i = tid; i < XINF; i += 256){
    int ch = i / 144, r = (i % 144) / 12, cc = i % 12;
    int gy = y0 - 3 + r, gx = x0 - 3 + cc;
    float v = 0.f;
    if (gy >= 0 && gy < 96 && gx >= 0 && gx < 96){
      if (REDB && ch >= nA && ch < nA + nB){
        float s = 0.f;
        #pragma unroll
        for (int cch = 0; cch < 16; ++cch) s += inB[((size_t)gy*16 + cch)*96 + gx];
        v = s;
      } else {
        const float* src = (ch < nA) ? (inA + (size_t)ch*IMG)
                         : (ch < nA+nB) ? (inB + (size_t)(ch-nA)*IMG)
                         : (inC + (size_t)(ch-nA-nB)*IMG);
        v = src[gy*96 + gx];
      }
    }
    xin[i] = v;
  }
  for (int i = tid; i < W1F; i += 256) w1s[i] = W1[i];
  if (tid < 32) S.b1[tid] = B1[tid];
  else if (tid < 64) S.b2[tid-32] = B2[tid-32];
  else if (tid < 64+COUT) S.b3[tid-64] = B3[tid-64];
  else if (tid == 96) S.al[0] = A1[0];
  else if (tid == 97) S.al[1] = A2[0];
  __syncthreads();

  // ---- conv1 (CIN -> 32) + PReLU ----
  {
    const int och = tid & 31, t = tid >> 5;
    const float al = S.al[0];
    for (int r = t; r < 10; r += 8){
      const int gy = y0 - 2 + r;
      float acc[10];
      #pragma unroll
      for (int cc = 0; cc < 10; ++cc) acc[cc] = S.b1[och];
      #pragma unroll
      for (int ci = 0; ci < CIN; ++ci){
        float xr[3][12];
        #pragma unroll
        for (int ky = 0; ky < 3; ++ky){
          #pragma unroll
          for (int j = 0; j < 3; ++j){
            vf4 q = *reinterpret_cast<const vf4*>(&xin[ci*144 + (r+ky)*12 + 4*j]);
            xr[ky][4*j+0]=q.x; xr[ky][4*j+1]=q.y; xr[ky][4*j+2]=q.z; xr[ky][4*j+3]=q.w;
          }
        }
        float wv[9];
        #pragma unroll
        for (int kk = 0; kk < 9; ++kk) wv[kk] = w1s[(och*CIN+ci)*9 + kk];
        #pragma unroll
        for (int ky = 0; ky < 3; ++ky)
          #pragma unroll
          for (int kx = 0; kx < 3; ++kx)
            #pragma unroll
            for (int cc = 0; cc < 10; ++cc)
              acc[cc] += xr[ky][cc+kx] * wv[ky*3+kx];
      }
      const bool yin = (gy >= 0 && gy < 96);
      #pragma unroll
      for (int cc = 0; cc < 10; ++cc){
        const int gx = x0 - 2 + cc;
        float v = acc[cc];
        v = (v >= 0.f) ? v : al*v;
        const bool in = yin && (gx >= 0 && gx < 96);
        S.c1s[(och*10 + r)*12 + cc] = in ? v : 0.f;
      }
    }
  }
  // ---- pull residual into regs before xin is overlaid ----
  float resv = 0.f;
  {
    int sp = tid % 36, och = tid / 36;
    if (och < COUT){
      int ty = sp / 6, tx = sp % 6;
      resv = xin[och*144 + (ty+3)*12 + (tx+3)];
    }
  }
  // ---- coalesced W2 load into registers (before barrier overlays xin) ----
  float w2r[36];
  {
    const vf4* src = reinterpret_cast<const vf4*>(W2 + (size_t)tid*36);
    #pragma unroll
    for (int q = 0; q < 9; ++q) reinterpret_cast<vf4*>(w2r)[q] = src[q];
  }
  __syncthreads();

  // ---- scatter W2 into overlay transposed: w2t[(ci*9+kk)*32 + och] ----
  float* w2t = S.ovl;
  {
    const int och = tid >> 3, k0 = (tid & 7)*36;
    #pragma unroll
    for (int j = 0; j < 36; ++j) w2t[(k0 + j)*32 + och] = w2r[j];
  }
  __syncthreads();

  // ---- conv2 (32 -> 32) + PReLU ----
  {
    const int och = tid & 31, ty = tid >> 5;  // ty 0..7
    const int gy = y0 - 1 + ty;
    const float al = S.al[1];
    float acc[8];
    #pragma unroll
    for (int cc = 0; cc < 8; ++cc) acc[cc] = S.b2[och];
    for (int ci = 0; ci < 32; ++ci){
      float cr[3][12];
      #pragma unroll
      for (int ky = 0; ky < 3; ++ky){
        #pragma unroll
        for (int j = 0; j < 3; ++j){
          vf4 q = *reinterpret_cast<const vf4*>(&S.c1s[(ci*10 + ty+ky)*12 + 4*j]);
          cr[ky][4*j+0]=q.x; cr[ky][4*j+1]=q.y; cr[ky][4*j+2]=q.z; cr[ky][4*j+3]=q.w;
        }
      }
      float wv[9];
      #pragma unroll
      for (int kk = 0; kk < 9; ++kk) wv[kk] = w2t[(ci*9+kk)*32 + och];
      #pragma unroll
      for (int ky = 0; ky < 3; ++ky)
        #pragma unroll
        for (int kx = 0; kx < 3; ++kx)
          #pragma unroll
          for (int cc = 0; cc < 8; ++cc)
            acc[cc] += cr[ky][cc+kx] * wv[ky*3+kx];
    }
    const bool yin = (gy >= 0 && gy < 96);
    #pragma unroll
    for (int cc = 0; cc < 8; ++cc){
      const int gx = x0 - 1 + cc;
      float v = acc[cc];
      v = (v >= 0.f) ? v : al*v;
      const bool in = yin && (gx >= 0 && gx < 96);
      S.c2s[(och*8 + ty)*9 + cc] = in ? v : 0.f;
    }
  }
  __syncthreads();

  // ---- load w3 into overlay ----
  float* w3s = S.ovl;
  for (int i = tid; i < W3F; i += 256) w3s[i] = W3[i];
  __syncthreads();

  // ---- conv3 (32 -> COUT) + bias + residual ----
  {
    int sp = tid % 36, och = tid / 36;
    if (och < COUT){
      int ty = sp / 6, tx = sp % 6;
      float acc = S.b3[och];
      for (int ci = 0; ci < 32; ++ci){
        #pragma unroll
        for (int ky = 0; ky < 3; ++ky)
          #pragma unroll
          for (int kx = 0; kx < 3; ++kx)
            acc += S.c2s[(ci*8 + ty+ky)*9 + (tx+kx)] * w3s[(och*32+ci)*9 + ky*3+kx];
      }
      const float vout = resv + acc;
      const int idx = (y0+ty)*96 + (x0+tx);
      out[(size_t)och*IMG + idx] = vout;
      if (out2 != nullptr && och == 0) out2[idx] = vout;
    }
  }
}

// ---------------- kernel wrappers ----------------
template<int MODE>
__global__ __launch_bounds__(256) void k_ev1_w(const float* Sf, __half* S16,
                                               const float* prim, float* part){
  __shared__ ShEv sh;
  ev1_task<MODE>(sh, blockIdx.x, blockIdx.y, Sf, S16, prim, part);
}

template<int MODE>
__global__ __launch_bounds__(256) void k_bp_w(const float* Sf, __half* S16,
                                              const float* dual, float* ev2){
  __shared__ ShBp sh;
  bp_task<MODE>(sh, blockIdx.x, Sf, S16, dual, ev2);
}

template<int CIN, int COUT, bool REDB>
__global__ __launch_bounds__(256) void k_conv_w(
    const float* inA, int nA, const float* inB, int nB, const float* inC,
    const float* W1, const float* B1, const float* A1,
    const float* W2, const float* B2, const float* A2,
    const float* W3, const float* B3, float* out, float* out2){
  __shared__ ShCv sh;
  conv_task<CIN,COUT,REDB>(sh, (blockIdx.x & 15)*6, (blockIdx.x >> 4)*6,
      inA, nA, inB, nB, inC, W1, B1, A1, W2, B2, A2, W3, B3, out, out2);
}

extern "C" void kernel_launch(void* const* d_in, const int* in_sizes, int n_in,
                              void* d_out, int out_size, void* d_ws, size_t ws_size,
                              hipStream_t stream){
  (void)in_sizes; (void)n_in; (void)out_size;
  const float* dual   = (const float*)d_in[0];
  const float* primal = (const float*)d_in[1];
  const float* proj   = (const float*)d_in[2];
  const float* S      = (const float*)d_in[3];
  const float* Snorm  = (const float*)d_in[4];
  const float* dW1 = (const float*)d_in[5];  const float* db1 = (const float*)d_in[6];
  const float* da1 = (const float*)d_in[7];
  const float* dW2 = (const float*)d_in[8];  const float* db2 = (const float*)d_in[9];
  const float* da2 = (const float*)d_in[10];
  const float* dW3 = (const float*)d_in[11]; const float* db3 = (const float*)d_in[12];
  const float* pW1 = (const float*)d_in[13]; const float* pb1 = (const float*)d_in[14];
  const float* pa1 = (const float*)d_in[15];
  const float* pW2 = (const float*)d_in[16]; const float* pb2 = (const float*)d_in[17];
  const float* pa2 = (const float*)d_in[18];
  const float* pW3 = (const float*)d_in[19]; const float* pb3 = (const float*)d_in[20];

  const size_t S16E = (size_t)96*PP*96;
  const size_t needFloats = (size_t)29*PP;
  const size_t need16 = 2*S16E*sizeof(__half) + needFloats*sizeof(float);
  const bool f16 = (ws_size >= need16);

  __half* S16n = nullptr; __half* S16s = nullptr; float* fbase;
  if (f16){
    S16n = (__half*)d_ws;
    S16s = S16n + S16E;
    fbase = (float*)(S16s + S16E);
  } else {
    fbase = (float*)d_ws;
  }
  float* dB0  = fbase;            fbase += PP;
  float* dB1  = fbase;            fbase += PP;
  float* pB0  = fbase;            fbase += NPRIM*PP;
  float* pB1  = fbase;            fbase += NPRIM*PP;
  float* part = fbase;            fbase += 16*PP;
  float* ev2  = fbase;            fbase += PP;

  for (int k = 0; k < NITER; ++k){
    const float* dcur = (k == 0) ? dual   : ((k & 1) ? dB0 : dB1);
    float*       dnxt = (k & 1) ? dB1 : dB0;
    const float* pcur = (k == 0) ? primal : ((k & 1) ? pB0 : pB1);
    float*       pnxt = (k & 1) ? pB1 : pB0;
    float*       out2 = (k == NITER-1) ? (float*)d_out : nullptr;

    if (f16){
      if (k == 0) k_ev1_w<1><<<dim3(96,16), 256, 0, stream>>>(Snorm, S16n, pcur, part);
      else        k_ev1_w<2><<<dim3(96,16), 256, 0, stream>>>(nullptr, S16n, pcur, part);
    } else        k_ev1_w<0><<<dim3(96,16), 256, 0, stream>>>(Snorm, nullptr, pcur, part);

    k_conv_w<3,1,true><<<256, 256, 0, stream>>>(
        dcur, 1, part, 1, proj,
        dW1 + (size_t)k*32*3*9, db1 + (size_t)k*32, da1 + k,
        dW2 + (size_t)k*32*32*9, db2 + (size_t)k*32, da2 + k,
        dW3 + (size_t)k*1*32*9, db3 + (size_t)k*1, dnxt, nullptr);

    if (f16){
      if (k == 0) k_bp_w<1><<<512, 256, 0, stream>>>(S, S16s, dnxt, ev2);
      else        k_bp_w<2><<<512, 256, 0, stream>>>(nullptr, S16s, dnxt, ev2);
    } else        k_bp_w<0><<<512, 256, 0, stream>>>(S, nullptr, dnxt, ev2);

    k_conv_w<6,5,false><<<256, 256, 0, stream>>>(
        pcur, 5, ev2, 1, ev2,
        pW1 + (size_t)k*32*6*9, pb1 + (size_t)k*32, pa1 + k,
        pW2 + (size_t)k*32*32*9, pb2 + (size_t)k*32, pa2 + k,
        pW3 + (size_t)k*5*32*9, pb3 + (size_t)k*5, pnxt, out2);
  }
}